// Round 1
// baseline (952.854 us; speedup 1.0000x reference)
//
#include <hip/hip_runtime.h>
#include <hip/hip_bf16.h>
#include <stdint.h>

typedef __hip_bfloat16 bf16;
typedef __attribute__((ext_vector_type(8))) short short8;
typedef __attribute__((ext_vector_type(4))) float f32x4;

#define BM 128
#define BN 128
#define BK 32
#define LDK 40  // padded LDS row stride (bf16 elems): 80B rows -> bank-spread, 16B aligned

__device__ __forceinline__ unsigned short f2bf_bits(float x) {
    return __builtin_bit_cast(unsigned short, __float2bfloat16(x));
}

// fp32 -> bf16, 4 elems/thread
__global__ void cvt_f32_bf16_x4(const float* __restrict__ in, unsigned short* __restrict__ out, int n4) {
    int i = blockIdx.x * 256 + threadIdx.x;
    if (i < n4) {
        float4 v = reinterpret_cast<const float4*>(in)[i];
        ushort4 o;
        o.x = f2bf_bits(v.x); o.y = f2bf_bits(v.y);
        o.z = f2bf_bits(v.z); o.w = f2bf_bits(v.w);
        reinterpret_cast<ushort4*>(out)[i] = o;
    }
}

// W[z] fp32 [1024][1024] -> Wt bf16 [z][n][k] (transposed)
__global__ void wtrans_kernel(const float* __restrict__ W0, const float* __restrict__ W1,
                              const float* __restrict__ W2, bf16* __restrict__ Wt) {
    __shared__ float tile[32][33];
    const int z = blockIdx.z;
    const float* in = (z == 0) ? W0 : (z == 1) ? W1 : W2;
    bf16* out = Wt + (size_t)z * 1024 * 1024;
    const int bx = blockIdx.x, by = blockIdx.y, tx = threadIdx.x;
    for (int r = threadIdx.y; r < 32; r += 8)
        tile[r][tx] = in[(size_t)(by * 32 + r) * 1024 + bx * 32 + tx];
    __syncthreads();
    for (int r = threadIdx.y; r < 32; r += 8)
        out[(size_t)(bx * 32 + r) * 1024 + by * 32 + tx] = __float2bfloat16(tile[tx][r]);
}

// bf16 transpose: in [rows][cols] -> out [cols][rows]
__global__ void tpose_bf16(const bf16* __restrict__ in, bf16* __restrict__ out, int rows, int cols) {
    __shared__ bf16 tile[32][33];
    const int bx = blockIdx.x, by = blockIdx.y, tx = threadIdx.x;
    for (int r = threadIdx.y; r < 32; r += 8)
        tile[r][tx] = in[(size_t)(by * 32 + r) * cols + bx * 32 + tx];
    __syncthreads();
    for (int r = threadIdx.y; r < 32; r += 8)
        out[(size_t)(bx * 32 + r) * rows + by * 32 + tx] = tile[tx][r];
}

// C[M][N] = A[M][K] * B[N][K]^T   (both operands K-contiguous, "BT" gemm)
// MODE 0: out_bf16 = C + bias[col], blockIdx.z selects {B,bias,out} slab (QKV)
// MODE 1: out_bf16 = exp(C*scale), atomicAdd row sums into lsum   (S chunk)
// MODE 2: out_f32  = C / lsum[row]                                 (O chunk)
template <int MODE>
__global__ __launch_bounds__(256, 2)
void gemm_bt(const bf16* __restrict__ A, const bf16* __restrict__ B,
             const float* __restrict__ b0, const float* __restrict__ b1,
             const float* __restrict__ b2, float* __restrict__ lsum,
             bf16* __restrict__ outb, float* __restrict__ outf,
             int M, int N, int K, int ldout, float scale) {
    __shared__ bf16 As[BM * LDK];
    __shared__ bf16 Bs[BN * LDK];

    const int tid  = threadIdx.x;
    const int lane = tid & 63;
    const int wave = tid >> 6;
    const int wm = wave & 1, wn = wave >> 1;
    const int l16  = lane & 15;
    const int quad = lane >> 4;
    const long bm0 = (long)blockIdx.x * BM;
    const long bn0 = (long)blockIdx.y * BN;

    const float* bias = nullptr;
    if (MODE == 0) {
        const int z = blockIdx.z;
        B    += (size_t)z * N * K;
        outb += (size_t)z * M * ldout;
        bias  = (z == 0) ? b0 : (z == 1) ? b1 : b2;
    }

    // staging: 256 threads x 16B = 64 rows x 32 cols per round, 2 rounds each
    const int srow = tid >> 2;
    const int scol = (tid & 3) * 8;
    const bf16* Ag0 = A + (size_t)(bm0 + srow) * K + scol;
    const bf16* Ag1 = Ag0 + (size_t)64 * K;
    const bf16* Bg0 = B + (size_t)(bn0 + srow) * K + scol;
    const bf16* Bg1 = Bg0 + (size_t)64 * K;
    bf16* Aw0 = As + srow * LDK + scol;
    bf16* Aw1 = Aw0 + 64 * LDK;
    bf16* Bw0 = Bs + srow * LDK + scol;
    bf16* Bw1 = Bw0 + 64 * LDK;

    const bf16* Ard = As + (wm * 64 + l16) * LDK + quad * 8;
    const bf16* Brd = Bs + (wn * 64 + l16) * LDK + quad * 8;

    f32x4 acc[4][4];
    const f32x4 zero = {0.f, 0.f, 0.f, 0.f};
#pragma unroll
    for (int i = 0; i < 4; i++)
#pragma unroll
        for (int j = 0; j < 4; j++) acc[i][j] = zero;

    for (int k0 = 0; k0 < K; k0 += BK) {
        uint4 a0 = *reinterpret_cast<const uint4*>(Ag0 + k0);
        uint4 a1 = *reinterpret_cast<const uint4*>(Ag1 + k0);
        uint4 v0 = *reinterpret_cast<const uint4*>(Bg0 + k0);
        uint4 v1 = *reinterpret_cast<const uint4*>(Bg1 + k0);
        __syncthreads();
        *reinterpret_cast<uint4*>(Aw0) = a0;
        *reinterpret_cast<uint4*>(Aw1) = a1;
        *reinterpret_cast<uint4*>(Bw0) = v0;
        *reinterpret_cast<uint4*>(Bw1) = v1;
        __syncthreads();
        short8 af[4], bfr[4];
#pragma unroll
        for (int mi = 0; mi < 4; mi++)
            af[mi] = *reinterpret_cast<const short8*>(Ard + mi * 16 * LDK);
#pragma unroll
        for (int ni = 0; ni < 4; ni++)
            bfr[ni] = *reinterpret_cast<const short8*>(Brd + ni * 16 * LDK);
#pragma unroll
        for (int mi = 0; mi < 4; mi++)
#pragma unroll
            for (int ni = 0; ni < 4; ni++)
                acc[mi][ni] = __builtin_amdgcn_mfma_f32_16x16x32_bf16(af[mi], bfr[ni], acc[mi][ni], 0, 0, 0);
    }

    // C/D layout (m89/m91 verified): col = lane&15, row = quad*4 + r
    const int rbase = wm * 64 + quad * 4;
    const int cbase = wn * 64 + l16;
    if (MODE == 0) {
#pragma unroll
        for (int mi = 0; mi < 4; mi++)
#pragma unroll
            for (int r = 0; r < 4; r++) {
                long row = bm0 + rbase + mi * 16 + r;
#pragma unroll
                for (int ni = 0; ni < 4; ni++) {
                    long col = bn0 + cbase + ni * 16;
                    outb[row * ldout + col] = __float2bfloat16(acc[mi][ni][r] + bias[col]);
                }
            }
    } else if (MODE == 1) {
#pragma unroll
        for (int mi = 0; mi < 4; mi++)
#pragma unroll
            for (int r = 0; r < 4; r++) {
                long row = bm0 + rbase + mi * 16 + r;
                float s = 0.f;
#pragma unroll
                for (int ni = 0; ni < 4; ni++) {
                    long col = bn0 + cbase + ni * 16;
                    float e = __expf(acc[mi][ni][r] * scale);
                    s += e;
                    outb[row * ldout + col] = __float2bfloat16(e);
                }
                s += __shfl_xor(s, 1);
                s += __shfl_xor(s, 2);
                s += __shfl_xor(s, 4);
                s += __shfl_xor(s, 8);
                if (l16 == 0) atomicAdd(&lsum[row], s);
            }
    } else {
#pragma unroll
        for (int mi = 0; mi < 4; mi++)
#pragma unroll
            for (int r = 0; r < 4; r++) {
                long row = bm0 + rbase + mi * 16 + r;
                float inv = 1.0f / lsum[row];
#pragma unroll
                for (int ni = 0; ni < 4; ni++) {
                    long col = bn0 + cbase + ni * 16;
                    outf[row * ldout + col] = acc[mi][ni][r] * inv;
                }
            }
    }
}

extern "C" void kernel_launch(void* const* d_in, const int* in_sizes, int n_in,
                              void* d_out, int out_size, void* d_ws, size_t ws_size,
                              hipStream_t stream) {
    const float* feat = (const float*)d_in[0];
    const float* Wq   = (const float*)d_in[1];
    const float* bqv  = (const float*)d_in[2];
    const float* Wk   = (const float*)d_in[3];
    const float* bkv  = (const float*)d_in[4];
    const float* Wv   = (const float*)d_in[5];
    const float* bvv  = (const float*)d_in[6];
    float* outp = (float*)d_out;

    const int M = 8192, D = 1024;
    char* ws = (char*)d_ws;
    size_t off = 0;
    auto carve = [&](size_t bytes) -> char* {
        char* r = ws + off;
        off += (bytes + 255) & ~(size_t)255;
        return r;
    };
    bf16* featb = (bf16*)carve((size_t)M * D * 2);      // dead after QKV gemm
    bf16* Wbt   = (bf16*)carve((size_t)3 * D * D * 2);  // dead after QKV gemm
    bf16* qkv   = (bf16*)carve((size_t)3 * M * D * 2);  // q | k | v slabs
    bf16* vbt   = (bf16*)carve((size_t)D * M * 2);
    float* lsum = (float*)carve((size_t)M * 4);
    size_t base = off;

    int chunk;
    bf16* Pc;
    if (ws_size >= base + (size_t)2048 * M * 2) {
        chunk = 2048;
        Pc = (bf16*)carve((size_t)2048 * M * 2);
    } else {
        chunk = 1024;          // alias dead featb region (16MB needed <= 23MB dead)
        Pc = (bf16*)d_ws;
    }

    // 1) feat -> bf16
    {
        int n4 = M * D / 4;
        cvt_f32_bf16_x4<<<dim3((n4 + 255) / 256), dim3(256), 0, stream>>>(feat, (unsigned short*)featb, n4);
    }
    // 2) W transpose+convert: Wbt[z][n][k]
    wtrans_kernel<<<dim3(32, 32, 3), dim3(32, 8), 0, stream>>>(Wq, Wk, Wv, Wbt);
    // 3) QKV projection
    gemm_bt<0><<<dim3(M / 128, D / 128, 3), dim3(256), 0, stream>>>(
        featb, Wbt, bqv, bkv, bvv, nullptr, qkv, nullptr, M, D, D, D, 1.0f);
    // 4) v -> v^T
    {
        bf16* vb = qkv + (size_t)2 * M * D;
        tpose_bf16<<<dim3(D / 32, M / 32), dim3(32, 8), 0, stream>>>(vb, vbt, M, D);
    }
    // 5) zero row sums
    hipMemsetAsync(lsum, 0, (size_t)M * 4, stream);
    // 6) chunked S = exp(q k^T / 32), then O = (S v) / rowsum
    const float scale = 0.03125f;  // 1/sqrt(1024)
    bf16* qb = qkv;
    bf16* kb = qkv + (size_t)M * D;
    for (int c0 = 0; c0 < M; c0 += chunk) {
        gemm_bt<1><<<dim3(chunk / 128, M / 128), dim3(256), 0, stream>>>(
            qb + (size_t)c0 * D, kb, nullptr, nullptr, nullptr, lsum + c0, Pc, nullptr,
            chunk, M, D, M, scale);
        gemm_bt<2><<<dim3(chunk / 128, D / 128), dim3(256), 0, stream>>>(
            Pc, vbt, nullptr, nullptr, nullptr, lsum + c0, nullptr, outp + (size_t)c0 * D,
            chunk, D, M, D, 0.f);
    }
}

// Round 2
// 668.864 us; speedup vs baseline: 1.4246x; 1.4246x over previous
//
#include <hip/hip_runtime.h>
#include <hip/hip_bf16.h>
#include <stdint.h>

typedef __hip_bfloat16 bf16;
typedef __attribute__((ext_vector_type(8))) short short8;
typedef __attribute__((ext_vector_type(4))) float f32x4;

#define BM 128
#define BN 128
#define BK 32

__device__ __forceinline__ unsigned short f2bf_bits(float x) {
    return __builtin_bit_cast(unsigned short, __float2bfloat16(x));
}

// async global->LDS, 16B per lane, LDS dest = wave-uniform base + lane*16
__device__ __forceinline__ void gload_lds16(const bf16* g, bf16* l) {
    __builtin_amdgcn_global_load_lds(
        (const __attribute__((address_space(1))) void*)(const void*)g,
        (__attribute__((address_space(3))) void*)(void*)l,
        16, 0, 0);
}

// fp32 -> bf16, 4 elems/thread
__global__ void cvt_f32_bf16_x4(const float* __restrict__ in, unsigned short* __restrict__ out, int n4) {
    int i = blockIdx.x * 256 + threadIdx.x;
    if (i < n4) {
        float4 v = reinterpret_cast<const float4*>(in)[i];
        ushort4 o;
        o.x = f2bf_bits(v.x); o.y = f2bf_bits(v.y);
        o.z = f2bf_bits(v.z); o.w = f2bf_bits(v.w);
        reinterpret_cast<ushort4*>(out)[i] = o;
    }
}

// W[z] fp32 [1024][1024] -> Wt bf16 [z][n][k] (transposed)
__global__ void wtrans_kernel(const float* __restrict__ W0, const float* __restrict__ W1,
                              const float* __restrict__ W2, bf16* __restrict__ Wt) {
    __shared__ float tile[32][33];
    const int z = blockIdx.z;
    const float* in = (z == 0) ? W0 : (z == 1) ? W1 : W2;
    bf16* out = Wt + (size_t)z * 1024 * 1024;
    const int bx = blockIdx.x, by = blockIdx.y, tx = threadIdx.x;
    for (int r = threadIdx.y; r < 32; r += 8)
        tile[r][tx] = in[(size_t)(by * 32 + r) * 1024 + bx * 32 + tx];
    __syncthreads();
    for (int r = threadIdx.y; r < 32; r += 8)
        out[(size_t)(bx * 32 + r) * 1024 + by * 32 + tx] = __float2bfloat16(tile[tx][r]);
}

// bf16 transpose: in [rows][cols] -> out [cols][rows]
__global__ void tpose_bf16(const bf16* __restrict__ in, bf16* __restrict__ out, int rows, int cols) {
    __shared__ bf16 tile[32][33];
    const int bx = blockIdx.x, by = blockIdx.y, tx = threadIdx.x;
    for (int r = threadIdx.y; r < 32; r += 8)
        tile[r][tx] = in[(size_t)(by * 32 + r) * cols + bx * 32 + tx];
    __syncthreads();
    for (int r = threadIdx.y; r < 32; r += 8)
        out[(size_t)(bx * 32 + r) * rows + by * 32 + tx] = tile[tx][r];
}

// out[row] scaled by 1/lsum[row]; one float4 per thread, 1024 cols = 256 float4/row
__global__ void scale_rows(float* __restrict__ out, const float* __restrict__ lsum) {
    int i = blockIdx.x * 256 + threadIdx.x;
    float4 v = reinterpret_cast<float4*>(out)[i];
    float inv = 1.0f / lsum[i >> 8];
    v.x *= inv; v.y *= inv; v.z *= inv; v.w *= inv;
    reinterpret_cast<float4*>(out)[i] = v;
}

// C[M][N] = A[M][K] * B[N][K]^T  (A row-stride K, B row-stride ldb; both K-contiguous)
// m97-style staging: global_load_lds dwordx4 into unpadded LDS [128][32].
// MODE 0: out_bf16 = C + bias[col], blockIdx.z selects {B,bias,out} slab (QKV)
// MODE 1: out_bf16 = exp(C*scale), atomicAdd row sums into lsum       (S chunk)
// MODE 2: out_f32 += C                                                 (O chunk, accumulate)
template <int MODE>
__global__ __launch_bounds__(256, 2)
void gemm_bt(const bf16* __restrict__ A, const bf16* __restrict__ B,
             const float* __restrict__ b0, const float* __restrict__ b1,
             const float* __restrict__ b2, float* __restrict__ lsum,
             bf16* __restrict__ outb, float* __restrict__ outf,
             int M, int N, int K, int ldb, int ldout, float scale) {
    __shared__ bf16 As[BM * BK];
    __shared__ bf16 Bs[BN * BK];

    const int tid  = threadIdx.x;
    const int lane = tid & 63;
    const int wave = tid >> 6;
    const int wm = wave & 1, wn = wave >> 1;
    const int l16  = lane & 15;
    const int quad = lane >> 4;
    const long bm0 = (long)blockIdx.x * BM;
    const long bn0 = (long)blockIdx.y * BN;

    const float* bias = nullptr;
    if (MODE == 0) {
        const int z = blockIdx.z;
        B    += (size_t)z * N * K;
        outb += (size_t)z * M * ldout;
        bias  = (z == 0) ? b0 : (z == 1) ? b1 : b2;
    }

    // staging: each wave DMAs two 16-row slabs of A and of B per iteration.
    // lane -> (row = base + lane>>2, col = (lane&3)*8): matches LDS base+lane*16.
    const int srow = wave * 32;
    const int lrow = lane >> 2;
    const int lcol = (lane & 3) * 8;
    const bf16* gA0 = A + (size_t)(bm0 + srow + lrow) * K + lcol;
    const bf16* gA1 = gA0 + (size_t)16 * K;
    const bf16* gB0 = B + (size_t)(bn0 + srow + lrow) * ldb + lcol;
    const bf16* gB1 = gB0 + (size_t)16 * ldb;
    bf16* lA0 = As + srow * BK;
    bf16* lA1 = As + (srow + 16) * BK;
    bf16* lB0 = Bs + srow * BK;
    bf16* lB1 = Bs + (srow + 16) * BK;

    const bf16* Ard = As + (wm * 64 + l16) * BK + quad * 8;
    const bf16* Brd = Bs + (wn * 64 + l16) * BK + quad * 8;

    f32x4 acc[4][4];
    const f32x4 zero = {0.f, 0.f, 0.f, 0.f};
#pragma unroll
    for (int i = 0; i < 4; i++)
#pragma unroll
        for (int j = 0; j < 4; j++) acc[i][j] = zero;

    for (int k0 = 0; k0 < K; k0 += BK) {
        __syncthreads();  // prior iteration's ds_reads complete before overwrite
        gload_lds16(gA0 + k0, lA0);
        gload_lds16(gA1 + k0, lA1);
        gload_lds16(gB0 + k0, lB0);
        gload_lds16(gB1 + k0, lB1);
        __syncthreads();  // compiler drains vmcnt(0) here -> LDS tiles ready
        short8 af[4], bfr[4];
#pragma unroll
        for (int mi = 0; mi < 4; mi++)
            af[mi] = *reinterpret_cast<const short8*>(Ard + mi * 16 * BK);
#pragma unroll
        for (int ni = 0; ni < 4; ni++)
            bfr[ni] = *reinterpret_cast<const short8*>(Brd + ni * 16 * BK);
#pragma unroll
        for (int mi = 0; mi < 4; mi++)
#pragma unroll
            for (int ni = 0; ni < 4; ni++)
                acc[mi][ni] = __builtin_amdgcn_mfma_f32_16x16x32_bf16(af[mi], bfr[ni], acc[mi][ni], 0, 0, 0);
    }

    // C/D layout (m89/m91 verified): col = lane&15, row = quad*4 + r
    const int rbase = wm * 64 + quad * 4;
    const int cbase = wn * 64 + l16;
    if (MODE == 0) {
#pragma unroll
        for (int mi = 0; mi < 4; mi++)
#pragma unroll
            for (int r = 0; r < 4; r++) {
                long row = bm0 + rbase + mi * 16 + r;
#pragma unroll
                for (int ni = 0; ni < 4; ni++) {
                    long col = bn0 + cbase + ni * 16;
                    outb[row * ldout + col] = __float2bfloat16(acc[mi][ni][r] + bias[col]);
                }
            }
    } else if (MODE == 1) {
#pragma unroll
        for (int mi = 0; mi < 4; mi++)
#pragma unroll
            for (int r = 0; r < 4; r++) {
                long row = bm0 + rbase + mi * 16 + r;
                float s = 0.f;
#pragma unroll
                for (int ni = 0; ni < 4; ni++) {
                    long col = bn0 + cbase + ni * 16;
                    float e = __expf(acc[mi][ni][r] * scale);
                    s += e;
                    outb[row * ldout + col] = __float2bfloat16(e);
                }
                s += __shfl_xor(s, 1);
                s += __shfl_xor(s, 2);
                s += __shfl_xor(s, 4);
                s += __shfl_xor(s, 8);
                if (l16 == 0) atomicAdd(&lsum[row], s);
            }
    } else {
#pragma unroll
        for (int mi = 0; mi < 4; mi++)
#pragma unroll
            for (int r = 0; r < 4; r++) {
                long row = bm0 + rbase + mi * 16 + r;
#pragma unroll
                for (int ni = 0; ni < 4; ni++) {
                    long col = bn0 + cbase + ni * 16;
                    outf[row * ldout + col] += acc[mi][ni][r];
                }
            }
    }
}

extern "C" void kernel_launch(void* const* d_in, const int* in_sizes, int n_in,
                              void* d_out, int out_size, void* d_ws, size_t ws_size,
                              hipStream_t stream) {
    const float* feat = (const float*)d_in[0];
    const float* Wq   = (const float*)d_in[1];
    const float* bqv  = (const float*)d_in[2];
    const float* Wk   = (const float*)d_in[3];
    const float* bkv  = (const float*)d_in[4];
    const float* Wv   = (const float*)d_in[5];
    const float* bvv  = (const float*)d_in[6];
    float* outp = (float*)d_out;

    const int M = 8192, D = 1024, C = 1024;  // C = key-chunk width
    char* ws = (char*)d_ws;
    size_t off = 0;
    auto carve = [&](size_t bytes) -> char* {
        char* r = ws + off;
        off += (bytes + 255) & ~(size_t)255;
        return r;
    };
    bf16* featb = (bf16*)carve((size_t)M * D * 2);      // dead after QKV gemm
    bf16* Wbt   = (bf16*)carve((size_t)3 * D * D * 2);  // dead after QKV gemm
    bf16* qkv   = (bf16*)carve((size_t)3 * M * D * 2);  // q | k | v slabs
    bf16* vbt   = (bf16*)carve((size_t)D * M * 2);      // v^T [D][M]
    float* lsum = (float*)carve((size_t)M * 4);
    bf16* Pc = featb;  // P chunk [M][C] = 16 MB, aliases dead featb

    // 1) feat -> bf16
    {
        int n4 = M * D / 4;
        cvt_f32_bf16_x4<<<dim3((n4 + 255) / 256), dim3(256), 0, stream>>>(feat, (unsigned short*)featb, n4);
    }
    // 2) W transpose+convert: Wbt[z][n][k]
    wtrans_kernel<<<dim3(32, 32, 3), dim3(32, 8), 0, stream>>>(Wq, Wk, Wv, Wbt);
    // 3) QKV projection (grid 64x8x3 = 1536 blocks)
    gemm_bt<0><<<dim3(M / 128, D / 128, 3), dim3(256), 0, stream>>>(
        featb, Wbt, bqv, bkv, bvv, nullptr, qkv, nullptr, M, D, D, D, D, 1.0f);
    // 4) v -> v^T
    {
        bf16* vb = qkv + (size_t)2 * M * D;
        tpose_bf16<<<dim3(D / 32, M / 32), dim3(32, 8), 0, stream>>>(vb, vbt, M, D);
    }
    // 5) zero row sums + output accumulator
    hipMemsetAsync(lsum, 0, (size_t)M * 4, stream);
    hipMemsetAsync(outp, 0, (size_t)M * D * 4, stream);
    // 6) key-chunked: P_c = exp(q k_c^T/32) [M x C], then out += P_c v_c; both grids 512 blocks
    const float scale = 0.03125f;  // 1/sqrt(1024)
    bf16* qb = qkv;
    bf16* kb = qkv + (size_t)M * D;
    for (int c = 0; c < M / C; c++) {
        gemm_bt<1><<<dim3(M / 128, C / 128), dim3(256), 0, stream>>>(
            qb, kb + (size_t)c * C * D, nullptr, nullptr, nullptr, lsum, Pc, nullptr,
            M, C, D, D, C, scale);
        gemm_bt<2><<<dim3(M / 128, D / 128), dim3(256), 0, stream>>>(
            Pc, vbt + (size_t)c * C, nullptr, nullptr, nullptr, nullptr, nullptr, outp,
            M, D, C, M, D, 0.f);
    }
    // 7) out /= rowsum
    scale_rows<<<dim3(M * D / 4 / 256), dim3(256), 0, stream>>>(outp, lsum);
}

// Round 3
// 516.430 us; speedup vs baseline: 1.8451x; 1.2952x over previous
//
#include <hip/hip_runtime.h>
#include <hip/hip_bf16.h>
#include <stdint.h>

typedef __hip_bfloat16 bf16;
typedef __attribute__((ext_vector_type(8))) short short8;
typedef __attribute__((ext_vector_type(4))) float f32x4;

#define BM 128
#define BN 128

__device__ __forceinline__ unsigned short f2bf_bits(float x) {
    return __builtin_bit_cast(unsigned short, __float2bfloat16(x));
}

// async global->LDS, 16B per lane, LDS dest = wave-uniform base + lane*16
__device__ __forceinline__ void gload_lds16(const bf16* g, bf16* l) {
    __builtin_amdgcn_global_load_lds(
        (const __attribute__((address_space(1))) void*)(const void*)g,
        (__attribute__((address_space(3))) void*)(void*)l,
        16, 0, 0);
}

__global__ void cvt_f32_bf16_x4(const float* __restrict__ in, unsigned short* __restrict__ out, int n4) {
    int i = blockIdx.x * 256 + threadIdx.x;
    if (i < n4) {
        float4 v = reinterpret_cast<const float4*>(in)[i];
        ushort4 o;
        o.x = f2bf_bits(v.x); o.y = f2bf_bits(v.y);
        o.z = f2bf_bits(v.z); o.w = f2bf_bits(v.w);
        reinterpret_cast<ushort4*>(out)[i] = o;
    }
}

// W[z] fp32 [1024][1024] -> Wt bf16 [z][n][k] (transposed)
__global__ void wtrans_kernel(const float* __restrict__ W0, const float* __restrict__ W1,
                              const float* __restrict__ W2, bf16* __restrict__ Wt) {
    __shared__ float tile[32][33];
    const int z = blockIdx.z;
    const float* in = (z == 0) ? W0 : (z == 1) ? W1 : W2;
    bf16* out = Wt + (size_t)z * 1024 * 1024;
    const int bx = blockIdx.x, by = blockIdx.y, tx = threadIdx.x;
    for (int r = threadIdx.y; r < 32; r += 8)
        tile[r][tx] = in[(size_t)(by * 32 + r) * 1024 + bx * 32 + tx];
    __syncthreads();
    for (int r = threadIdx.y; r < 32; r += 8)
        out[(size_t)(bx * 32 + r) * 1024 + by * 32 + tx] = __float2bfloat16(tile[tx][r]);
}

// bf16 transpose: in [rows][cols] -> out [cols][rows]
__global__ void tpose_bf16(const bf16* __restrict__ in, bf16* __restrict__ out, int rows, int cols) {
    __shared__ bf16 tile[32][33];
    const int bx = blockIdx.x, by = blockIdx.y, tx = threadIdx.x;
    for (int r = threadIdx.y; r < 32; r += 8)
        tile[r][tx] = in[(size_t)(by * 32 + r) * cols + bx * 32 + tx];
    __syncthreads();
    for (int r = threadIdx.y; r < 32; r += 8)
        out[(size_t)(bx * 32 + r) * rows + by * 32 + tx] = tile[tx][r];
}

__global__ void scale_rows(float* __restrict__ out, const float* __restrict__ lsum) {
    int i = blockIdx.x * 256 + threadIdx.x;
    float4 v = reinterpret_cast<float4*>(out)[i];
    float inv = 1.0f / lsum[i >> 8];
    v.x *= inv; v.y *= inv; v.z *= inv; v.w *= inv;
    reinterpret_cast<float4*>(out)[i] = v;
}

// C[M][N] = A[M][K] * B[N][K]^T   (A row-stride = K, B row-stride = ldb)
// MODE 0: outb = C + bias[col]  (z-slab QKV), LDS-staged coalesced bf16 stores
// MODE 1: outb = exp(C*scale), atomicAdd row-sums -> lsum, LDS-staged stores
// MODE 2: outf += C                      (chunked O fallback)
// MODE 3: outf  = C / lsum[row]          (full-P O path)
template <int MODE, int BKT>
__global__ __launch_bounds__(256, 2)
void gemm_bt(const bf16* __restrict__ A, const bf16* __restrict__ B,
             const float* __restrict__ b0, const float* __restrict__ b1,
             const float* __restrict__ b2, float* __restrict__ lsum,
             bf16* __restrict__ outb, float* __restrict__ outf,
             int M, int N, int K, int ldb, int ldout, float scale) {
    // BKT==32: 16 KB tiles + 2.3 KB/wave epilogue staging (overlaps tiles, post-barrier)
    constexpr int SELEMS = (BKT == 32) ? 9216 : BM * BKT * 2;
    __shared__ bf16 smem[SELEMS];
    bf16* As = smem;
    bf16* Bs = smem + BM * BKT;

    const int tid  = threadIdx.x;
    const int lane = tid & 63;
    const int wave = tid >> 6;
    const int wm = wave & 1, wn = wave >> 1;
    const int l16  = lane & 15;
    const int quad = lane >> 4;
    const long bm0 = (long)blockIdx.x * BM;
    const long bn0 = (long)blockIdx.y * BN;

    const float* bias = nullptr;
    if (MODE == 0) {
        const int z = blockIdx.z;
        B    += (size_t)z * N * K;
        outb += (size_t)z * M * ldout;
        bias  = (z == 0) ? b0 : (z == 1) ? b1 : b2;
    }

    constexpr int NLD = (BKT == 32) ? 2 : 4;
    const bf16* gA[NLD];
    const bf16* gB[NLD];
    bf16* lA[NLD];
    bf16* lB[NLD];
    if constexpr (BKT == 32) {
        const int lrow = lane >> 2, lcol = (lane & 3) * 8;  // 16-row slabs
#pragma unroll
        for (int u = 0; u < 2; u++) {
            gA[u] = A + (size_t)(bm0 + wave * 32 + u * 16 + lrow) * K + lcol;
            gB[u] = B + (size_t)(bn0 + wave * 32 + u * 16 + lrow) * ldb + lcol;
            lA[u] = As + (wave * 32 + u * 16) * BKT;
            lB[u] = Bs + (wave * 32 + u * 16) * BKT;
        }
    } else {
        const int lrow = lane >> 3, lcol = (lane & 7) * 8;  // 8-row slabs
#pragma unroll
        for (int u = 0; u < 4; u++) {
            gA[u] = A + (size_t)(bm0 + wave * 32 + u * 8 + lrow) * K + lcol;
            gB[u] = B + (size_t)(bn0 + wave * 32 + u * 8 + lrow) * ldb + lcol;
            lA[u] = As + (wave * 32 + u * 8) * BKT;
            lB[u] = Bs + (wave * 32 + u * 8) * BKT;
        }
    }

    const bf16* Ard = As + (wm * 64 + l16) * BKT + quad * 8;
    const bf16* Brd = Bs + (wn * 64 + l16) * BKT + quad * 8;

    f32x4 acc[4][4];
    const f32x4 zero = {0.f, 0.f, 0.f, 0.f};
#pragma unroll
    for (int i = 0; i < 4; i++)
#pragma unroll
        for (int j = 0; j < 4; j++) acc[i][j] = zero;

    for (int k0 = 0; k0 < K; k0 += BKT) {
        __syncthreads();
#pragma unroll
        for (int u = 0; u < NLD; u++) {
            gload_lds16(gA[u] + k0, lA[u]);
            gload_lds16(gB[u] + k0, lB[u]);
        }
        __syncthreads();
#pragma unroll
        for (int t = 0; t < BKT / 32; t++) {
            short8 af[4], bfr[4];
#pragma unroll
            for (int mi = 0; mi < 4; mi++)
                af[mi] = *reinterpret_cast<const short8*>(Ard + mi * 16 * BKT + t * 32);
#pragma unroll
            for (int ni = 0; ni < 4; ni++)
                bfr[ni] = *reinterpret_cast<const short8*>(Brd + ni * 16 * BKT + t * 32);
#pragma unroll
            for (int mi = 0; mi < 4; mi++)
#pragma unroll
                for (int ni = 0; ni < 4; ni++)
                    acc[mi][ni] = __builtin_amdgcn_mfma_f32_16x16x32_bf16(af[mi], bfr[ni], acc[mi][ni], 0, 0, 0);
        }
    }

    // C/D layout (m89/m91): col = lane&15, row = quad*4 + r
    if (MODE == 0 || MODE == 1) {
        __syncthreads();  // tiles dead; reuse smem for epilogue staging
        bf16* eb = smem + wave * 1152;  // 16 rows x stride-72 bf16 = 2304 B / wave
        float bcol[4];
        if (MODE == 0) {
#pragma unroll
            for (int ni = 0; ni < 4; ni++) bcol[ni] = bias[bn0 + wn * 64 + l16 + ni * 16];
        }
#pragma unroll
        for (int mi = 0; mi < 4; mi++) {
#pragma unroll
            for (int r = 0; r < 4; r++) {
                float s = 0.f;
#pragma unroll
                for (int ni = 0; ni < 4; ni++) {
                    float v = acc[mi][ni][r];
                    if (MODE == 0) v += bcol[ni];
                    else { v = __expf(v * scale); s += v; }
                    eb[(quad * 4 + r) * 72 + ni * 16 + l16] = __float2bfloat16(v);
                }
                if (MODE == 1) {
                    s += __shfl_xor(s, 1);
                    s += __shfl_xor(s, 2);
                    s += __shfl_xor(s, 4);
                    s += __shfl_xor(s, 8);
                    if (l16 == 0) atomicAdd(&lsum[bm0 + wm * 64 + mi * 16 + quad * 4 + r], s);
                }
            }
            asm volatile("s_waitcnt lgkmcnt(0)" ::: "memory");
#pragma unroll
            for (int p = 0; p < 2; p++) {
                int r2 = p * 8 + (lane >> 3);
                int c2 = (lane & 7) * 8;
                short8 val = *reinterpret_cast<const short8*>(eb + r2 * 72 + c2);
                *reinterpret_cast<short8*>(
                    outb + (size_t)(bm0 + wm * 64 + mi * 16 + r2) * ldout + bn0 + wn * 64 + c2) = val;
            }
            asm volatile("s_waitcnt lgkmcnt(0)" ::: "memory");  // reads done before next slice overwrites
        }
    } else {
        const int rb2 = wm * 64 + quad * 4;
        const int cb2 = wn * 64 + l16;
#pragma unroll
        for (int mi = 0; mi < 4; mi++)
#pragma unroll
            for (int r = 0; r < 4; r++) {
                long row = bm0 + rb2 + mi * 16 + r;
                float mul = (MODE == 3) ? 1.0f / lsum[row] : 0.f;
#pragma unroll
                for (int ni = 0; ni < 4; ni++) {
                    long col = bn0 + cb2 + ni * 16;
                    if (MODE == 3) outf[row * ldout + col] = acc[mi][ni][r] * mul;
                    else           outf[row * ldout + col] += acc[mi][ni][r];
                }
            }
    }
}

extern "C" void kernel_launch(void* const* d_in, const int* in_sizes, int n_in,
                              void* d_out, int out_size, void* d_ws, size_t ws_size,
                              hipStream_t stream) {
    const float* feat = (const float*)d_in[0];
    const float* Wq   = (const float*)d_in[1];
    const float* bqv  = (const float*)d_in[2];
    const float* Wk   = (const float*)d_in[3];
    const float* bkv  = (const float*)d_in[4];
    const float* Wv   = (const float*)d_in[5];
    const float* bvv  = (const float*)d_in[6];
    float* outp = (float*)d_out;

    const int M = 8192, D = 1024;
    char* ws = (char*)d_ws;
    size_t off = 0;
    auto carve = [&](size_t bytes) -> char* {
        char* r = ws + off;
        off += (bytes + 255) & ~(size_t)255;
        return r;
    };
    bf16* featb = (bf16*)carve((size_t)M * D * 2);      // dead after QKV gemm
    bf16* Wbt   = (bf16*)carve((size_t)3 * D * D * 2);  // dead after QKV gemm
    bf16* qkv   = (bf16*)carve((size_t)3 * M * D * 2);  // q | k | v slabs
    float* lsum = (float*)carve((size_t)M * 4);
    bf16* vbt   = featb;  // v^T [D][M], aliases dead featb (tpose runs after QKV)
    size_t avail = (ws_size > off) ? ws_size - off : 0;

    int C;  // key-chunk width for P
    if      (avail >= (size_t)M * M * 2)    C = M;     // full P, 128 MB
    else if (avail >= (size_t)M * 4096 * 2) C = 4096;
    else if (avail >= (size_t)M * 2048 * 2) C = 2048;
    else                                    C = 1024;
    bf16* Pc = (bf16*)carve((size_t)M * C * 2);

    // 1) feat -> bf16
    {
        int n4 = M * D / 4;
        cvt_f32_bf16_x4<<<dim3((n4 + 255) / 256), dim3(256), 0, stream>>>(feat, (unsigned short*)featb, n4);
    }
    // 2) W transpose+convert
    wtrans_kernel<<<dim3(32, 32, 3), dim3(32, 8), 0, stream>>>(Wq, Wk, Wv, Wbt);
    // 3) QKV projection
    gemm_bt<0, 32><<<dim3(M / 128, D / 128, 3), dim3(256), 0, stream>>>(
        featb, Wbt, bqv, bkv, bvv, nullptr, qkv, nullptr, M, D, D, D, D, 1.0f);
    // 4) v -> v^T
    tpose_bf16<<<dim3(D / 32, M / 32), dim3(32, 8), 0, stream>>>(qkv + (size_t)2 * M * D, vbt, M, D);
    // 5) row sums
    hipMemsetAsync(lsum, 0, (size_t)M * 4, stream);

    const float scale = 0.03125f;  // 1/sqrt(1024)
    bf16* qb = qkv;
    bf16* kb = qkv + (size_t)M * D;
    if (C == M) {
        // 6a) full P = exp(q k^T/32): grid 64x64 = 4096 blocks (16/CU)
        gemm_bt<1, 32><<<dim3(M / 128, M / 128), dim3(256), 0, stream>>>(
            qb, kb, nullptr, nullptr, nullptr, lsum, Pc, nullptr, M, M, D, D, M, scale);
        // 7a) out = (P v) / lsum in one K=8192 gemm, BK=64, no RMW
        gemm_bt<3, 64><<<dim3(M / 128, D / 128), dim3(256), 0, stream>>>(
            Pc, vbt, nullptr, nullptr, nullptr, lsum, nullptr, outp, M, D, M, M, D, 0.f);
    } else {
        hipMemsetAsync(outp, 0, (size_t)M * D * 4, stream);
        for (int c = 0; c < M / C; c++) {
            gemm_bt<1, 32><<<dim3(M / 128, C / 128), dim3(256), 0, stream>>>(
                qb, kb + (size_t)c * C * D, nullptr, nullptr, nullptr, lsum, Pc, nullptr,
                M, C, D, D, C, scale);
            gemm_bt<2, 64><<<dim3(M / 128, D / 128), dim3(256), 0, stream>>>(
                Pc, vbt + (size_t)c * C, nullptr, nullptr, nullptr, nullptr, nullptr, outp,
                M, D, C, M, D, 0.f);
        }
        scale_rows<<<dim3(M * D / 4 / 256), dim3(256), 0, stream>>>(outp, lsum);
    }
}

// Round 4
// 477.550 us; speedup vs baseline: 1.9953x; 1.0814x over previous
//
#include <hip/hip_runtime.h>
#include <hip/hip_bf16.h>
#include <stdint.h>

typedef __hip_bfloat16 bf16;
typedef __attribute__((ext_vector_type(8))) short short8;
typedef __attribute__((ext_vector_type(4))) float f32x4;

#define BM 128
#define BN 128

__device__ __forceinline__ unsigned short f2bf_bits(float x) {
    return __builtin_bit_cast(unsigned short, __float2bfloat16(x));
}

// async global->LDS, 16B per lane, LDS dest = wave-uniform base + lane*16
__device__ __forceinline__ void gload_lds16(const bf16* g, bf16* l) {
    __builtin_amdgcn_global_load_lds(
        (const __attribute__((address_space(1))) void*)(const void*)g,
        (__attribute__((address_space(3))) void*)(void*)l,
        16, 0, 0);
}

__global__ void cvt_f32_bf16_x4(const float* __restrict__ in, unsigned short* __restrict__ out, int n4) {
    int i = blockIdx.x * 256 + threadIdx.x;
    if (i < n4) {
        float4 v = reinterpret_cast<const float4*>(in)[i];
        ushort4 o;
        o.x = f2bf_bits(v.x); o.y = f2bf_bits(v.y);
        o.z = f2bf_bits(v.z); o.w = f2bf_bits(v.w);
        reinterpret_cast<ushort4*>(out)[i] = o;
    }
}

// W[z] fp32 [1024][1024] -> Wt bf16 [z][n][k] (transposed)
__global__ void wtrans_kernel(const float* __restrict__ W0, const float* __restrict__ W1,
                              const float* __restrict__ W2, bf16* __restrict__ Wt) {
    __shared__ float tile[32][33];
    const int z = blockIdx.z;
    const float* in = (z == 0) ? W0 : (z == 1) ? W1 : W2;
    bf16* out = Wt + (size_t)z * 1024 * 1024;
    const int bx = blockIdx.x, by = blockIdx.y, tx = threadIdx.x;
    for (int r = threadIdx.y; r < 32; r += 8)
        tile[r][tx] = in[(size_t)(by * 32 + r) * 1024 + bx * 32 + tx];
    __syncthreads();
    for (int r = threadIdx.y; r < 32; r += 8)
        out[(size_t)(bx * 32 + r) * 1024 + by * 32 + tx] = __float2bfloat16(tile[tx][r]);
}

// bf16 transpose: in [rows][cols] -> out [cols][rows]
__global__ void tpose_bf16(const bf16* __restrict__ in, bf16* __restrict__ out, int rows, int cols) {
    __shared__ bf16 tile[32][33];
    const int bx = blockIdx.x, by = blockIdx.y, tx = threadIdx.x;
    for (int r = threadIdx.y; r < 32; r += 8)
        tile[r][tx] = in[(size_t)(by * 32 + r) * cols + bx * 32 + tx];
    __syncthreads();
    for (int r = threadIdx.y; r < 32; r += 8)
        out[(size_t)(bx * 32 + r) * rows + by * 32 + tx] = tile[tx][r];
}

__global__ void scale_rows(float* __restrict__ out, const float* __restrict__ lsum) {
    int i = blockIdx.x * 256 + threadIdx.x;
    float4 v = reinterpret_cast<float4*>(out)[i];
    float inv = 1.0f / lsum[i >> 8];
    v.x *= inv; v.y *= inv; v.z *= inv; v.w *= inv;
    reinterpret_cast<float4*>(out)[i] = v;
}

// C[M][N] = A[M][K] * B[N][K]^T   (A row-stride = K, B row-stride = ldb)
// LDS tiles stored as KH stacked [128][32] half-tiles (64 B row stride ->
// conflict-free b128 fragment reads; 128 B stride was an 8-way conflict).
// MODE 0: outb = C + bias[col]  (z-slab QKV), LDS-staged coalesced bf16 stores
// MODE 1: outb = exp(C*scale), atomicAdd row-sums -> lsum, LDS-staged stores
// MODE 2: outf += C                      (chunked O fallback)
// MODE 3: outf  = C / lsum[row]          (full-P O path)
template <int MODE, int KH>   // KH = BK/32
__global__ __launch_bounds__(256, 2)
void gemm_bt(const bf16* __restrict__ A, const bf16* __restrict__ B,
             const float* __restrict__ b0, const float* __restrict__ b1,
             const float* __restrict__ b2, float* __restrict__ lsum,
             bf16* __restrict__ outb, float* __restrict__ outf,
             int M, int N, int K, int ldb, int ldout, float scale) {
    constexpr int BKT  = KH * 32;
    constexpr int TILE = 128 * 32;  // elems per half-tile per operand
    constexpr int SELEMS = (2 * KH * TILE < 9216) ? 9216 : 2 * KH * TILE;
    __shared__ bf16 smem[SELEMS];
    bf16* As = smem;             // As + h*TILE
    bf16* Bs = smem + KH * TILE; // Bs + h*TILE

    const int tid  = threadIdx.x;
    const int lane = tid & 63;
    const int wave = tid >> 6;
    const int wm = wave & 1, wn = wave >> 1;
    const int l16  = lane & 15;
    const int quad = lane >> 4;
    const long bm0 = (long)blockIdx.x * BM;
    const long bn0 = (long)blockIdx.y * BN;

    const float* bias = nullptr;
    if (MODE == 0) {
        const int z = blockIdx.z;
        B    += (size_t)z * N * K;
        outb += (size_t)z * M * ldout;
        bias  = (z == 0) ? b0 : (z == 1) ? b1 : b2;
    }

    // staging: per wave, rows [wave*32, wave*32+32); u = 16-row slab, h = K-half.
    // lane -> (row += lane>>2, col = (lane&3)*8) matches LDS base + lane*16.
    const int lrow = lane >> 2;
    const int lcol = (lane & 3) * 8;
    const bf16* gA[2][KH];
    const bf16* gB[2][KH];
    bf16* lA[2][KH];
    bf16* lB[2][KH];
#pragma unroll
    for (int u = 0; u < 2; u++)
#pragma unroll
        for (int h = 0; h < KH; h++) {
            gA[u][h] = A + (size_t)(bm0 + wave * 32 + u * 16 + lrow) * K + h * 32 + lcol;
            gB[u][h] = B + (size_t)(bn0 + wave * 32 + u * 16 + lrow) * ldb + h * 32 + lcol;
            lA[u][h] = As + h * TILE + (wave * 32 + u * 16) * 32;
            lB[u][h] = Bs + h * TILE + (wave * 32 + u * 16) * 32;
        }

    const bf16* Ard = As + (wm * 64 + l16) * 32 + quad * 8;
    const bf16* Brd = Bs + (wn * 64 + l16) * 32 + quad * 8;

    f32x4 acc[4][4];
    const f32x4 zero = {0.f, 0.f, 0.f, 0.f};
#pragma unroll
    for (int i = 0; i < 4; i++)
#pragma unroll
        for (int j = 0; j < 4; j++) acc[i][j] = zero;

    for (int k0 = 0; k0 < K; k0 += BKT) {
        __syncthreads();
#pragma unroll
        for (int u = 0; u < 2; u++)
#pragma unroll
            for (int h = 0; h < KH; h++) {
                gload_lds16(gA[u][h] + k0, lA[u][h]);
                gload_lds16(gB[u][h] + k0, lB[u][h]);
            }
        __syncthreads();
#pragma unroll
        for (int h = 0; h < KH; h++) {
            short8 af[4], bfr[4];
#pragma unroll
            for (int mi = 0; mi < 4; mi++)
                af[mi] = *reinterpret_cast<const short8*>(Ard + h * TILE + mi * 16 * 32);
#pragma unroll
            for (int ni = 0; ni < 4; ni++)
                bfr[ni] = *reinterpret_cast<const short8*>(Brd + h * TILE + ni * 16 * 32);
#pragma unroll
            for (int mi = 0; mi < 4; mi++)
#pragma unroll
                for (int ni = 0; ni < 4; ni++)
                    acc[mi][ni] = __builtin_amdgcn_mfma_f32_16x16x32_bf16(af[mi], bfr[ni], acc[mi][ni], 0, 0, 0);
        }
    }

    // C/D layout (m89/m91): col = lane&15, row = quad*4 + r
    if (MODE == 0 || MODE == 1) {
        __syncthreads();  // tiles dead; reuse smem for epilogue staging
        bf16* eb = smem + wave * 1152;  // 16 rows x stride-72 bf16 = 2304 B / wave
        float bcol[4];
        if (MODE == 0) {
#pragma unroll
            for (int ni = 0; ni < 4; ni++) bcol[ni] = bias[bn0 + wn * 64 + l16 + ni * 16];
        }
#pragma unroll
        for (int mi = 0; mi < 4; mi++) {
#pragma unroll
            for (int r = 0; r < 4; r++) {
                float s = 0.f;
#pragma unroll
                for (int ni = 0; ni < 4; ni++) {
                    float v = acc[mi][ni][r];
                    if (MODE == 0) v += bcol[ni];
                    else { v = __expf(v * scale); s += v; }
                    eb[(quad * 4 + r) * 72 + ni * 16 + l16] = __float2bfloat16(v);
                }
                if (MODE == 1) {
                    s += __shfl_xor(s, 1);
                    s += __shfl_xor(s, 2);
                    s += __shfl_xor(s, 4);
                    s += __shfl_xor(s, 8);
                    if (l16 == 0) atomicAdd(&lsum[bm0 + wm * 64 + mi * 16 + quad * 4 + r], s);
                }
            }
            asm volatile("s_waitcnt lgkmcnt(0)" ::: "memory");
#pragma unroll
            for (int p = 0; p < 2; p++) {
                int r2 = p * 8 + (lane >> 3);
                int c2 = (lane & 7) * 8;
                short8 val = *reinterpret_cast<const short8*>(eb + r2 * 72 + c2);
                *reinterpret_cast<short8*>(
                    outb + (size_t)(bm0 + wm * 64 + mi * 16 + r2) * ldout + bn0 + wn * 64 + c2) = val;
            }
            asm volatile("s_waitcnt lgkmcnt(0)" ::: "memory");
        }
    } else {
        const int rb2 = wm * 64 + quad * 4;
        const int cb2 = wn * 64 + l16;
#pragma unroll
        for (int mi = 0; mi < 4; mi++)
#pragma unroll
            for (int r = 0; r < 4; r++) {
                long row = bm0 + rb2 + mi * 16 + r;
                float mul = (MODE == 3) ? 1.0f / lsum[row] : 0.f;
#pragma unroll
                for (int ni = 0; ni < 4; ni++) {
                    long col = bn0 + cb2 + ni * 16;
                    if (MODE == 3) outf[row * ldout + col] = acc[mi][ni][r] * mul;
                    else           outf[row * ldout + col] += acc[mi][ni][r];
                }
            }
    }
}

extern "C" void kernel_launch(void* const* d_in, const int* in_sizes, int n_in,
                              void* d_out, int out_size, void* d_ws, size_t ws_size,
                              hipStream_t stream) {
    const float* feat = (const float*)d_in[0];
    const float* Wq   = (const float*)d_in[1];
    const float* bqv  = (const float*)d_in[2];
    const float* Wk   = (const float*)d_in[3];
    const float* bkv  = (const float*)d_in[4];
    const float* Wv   = (const float*)d_in[5];
    const float* bvv  = (const float*)d_in[6];
    float* outp = (float*)d_out;

    const int M = 8192, D = 1024;
    char* ws = (char*)d_ws;
    size_t off = 0;
    auto carve = [&](size_t bytes) -> char* {
        char* r = ws + off;
        off += (bytes + 255) & ~(size_t)255;
        return r;
    };
    bf16* featb = (bf16*)carve((size_t)M * D * 2);      // dead after QKV gemm
    bf16* Wbt   = (bf16*)carve((size_t)3 * D * D * 2);  // dead after QKV gemm
    bf16* qkv   = (bf16*)carve((size_t)3 * M * D * 2);  // q | k | v slabs
    float* lsum = (float*)carve((size_t)M * 4);
    bf16* vbt   = featb;  // v^T [D][M], aliases dead featb (tpose runs after QKV)
    size_t avail = (ws_size > off) ? ws_size - off : 0;

    int C;  // key-chunk width for P
    if      (avail >= (size_t)M * M * 2)    C = M;     // full P, 128 MB
    else if (avail >= (size_t)M * 4096 * 2) C = 4096;
    else if (avail >= (size_t)M * 2048 * 2) C = 2048;
    else                                    C = 1024;
    bf16* Pc = (bf16*)carve((size_t)M * C * 2);

    // 1) feat -> bf16
    {
        int n4 = M * D / 4;
        cvt_f32_bf16_x4<<<dim3((n4 + 255) / 256), dim3(256), 0, stream>>>(feat, (unsigned short*)featb, n4);
    }
    // 2) W transpose+convert
    wtrans_kernel<<<dim3(32, 32, 3), dim3(32, 8), 0, stream>>>(Wq, Wk, Wv, Wbt);
    // 3) QKV projection
    gemm_bt<0, 1><<<dim3(M / 128, D / 128, 3), dim3(256), 0, stream>>>(
        featb, Wbt, bqv, bkv, bvv, nullptr, qkv, nullptr, M, D, D, D, D, 1.0f);
    // 4) v -> v^T
    tpose_bf16<<<dim3(D / 32, M / 32), dim3(32, 8), 0, stream>>>(qkv + (size_t)2 * M * D, vbt, M, D);
    // 5) row sums
    hipMemsetAsync(lsum, 0, (size_t)M * 4, stream);

    const float scale = 0.03125f;  // 1/sqrt(1024)
    bf16* qb = qkv;
    bf16* kb = qkv + (size_t)M * D;
    if (C == M) {
        // 6a) full P = exp(q k^T/32): grid 64x64 = 4096 blocks
        gemm_bt<1, 1><<<dim3(M / 128, M / 128), dim3(256), 0, stream>>>(
            qb, kb, nullptr, nullptr, nullptr, lsum, Pc, nullptr, M, M, D, D, M, scale);
        // 7a) out = (P v) / lsum in one K=8192 gemm, BK=64 (2 half-tiles), no RMW
        gemm_bt<3, 2><<<dim3(M / 128, D / 128), dim3(256), 0, stream>>>(
            Pc, vbt, nullptr, nullptr, nullptr, lsum, nullptr, outp, M, D, M, M, D, 0.f);
    } else {
        hipMemsetAsync(outp, 0, (size_t)M * D * 4, stream);
        for (int c = 0; c < M / C; c++) {
            gemm_bt<1, 1><<<dim3(M / 128, C / 128), dim3(256), 0, stream>>>(
                qb, kb + (size_t)c * C * D, nullptr, nullptr, nullptr, lsum, Pc, nullptr,
                M, C, D, D, C, scale);
            gemm_bt<2, 2><<<dim3(M / 128, D / 128), dim3(256), 0, stream>>>(
                Pc, vbt + (size_t)c * C, nullptr, nullptr, nullptr, nullptr, nullptr, outp,
                M, D, C, M, D, 0.f);
        }
        scale_rows<<<dim3(M * D / 4 / 256), dim3(256), 0, stream>>>(outp, lsum);
    }
}